// Round 6
// baseline (77.304 us; speedup 1.0000x reference)
//
#include <hip/hip_runtime.h>
#include <stdint.h>

#define TOKENS 32768
#define IN_F   512
#define OUT_F  512
#define KW     16          // 512 bits -> 16 u32 words per row

typedef float f32x4 __attribute__((ext_vector_type(4)));

// ---------------------------------------------------------------------------
// Bit-packing permutation (identical for x and w, so XOR+popc dot products
// are unaffected): from a row read as float4[128] (index f, lane l), word
// k = f_hi*8 + c*2 + h holds in bit l the sign of float4 #(f_hi*64+l)
// element c (h selects lanes 0..31 / 32..63).
//
// ws layout: wbT[KW][OUT_F] at offset 0 (32 KB); xb[TOKENS][KW] at 32 KB (2 MB).
// ---------------------------------------------------------------------------

// Kernel 1: pack x rows (blocks 0..2047, 4 waves x 4 rows each) and
// w rows minus threshold (blocks 2048..2175, wave per output row).
__global__ __launch_bounds__(256) void pack_kernel(
    const float* __restrict__ x,      // [TOKENS][IN_F]
    const float* __restrict__ w,      // [OUT_F][IN_F]
    const float* __restrict__ thr,    // [OUT_F]
    uint32_t* __restrict__ xb,        // [TOKENS][KW]
    uint32_t* __restrict__ wbT)       // [KW][OUT_F]
{
    const int lane = threadIdx.x & 63;
    const int wid  = threadIdx.x >> 6;

    if (blockIdx.x < 2048) {
        // ---- x pack: pure read stream, 64 B of bits out per row ----
        const int g = blockIdx.x * 4 + wid;           // 0..8191
        const float4* xr = (const float4*)x;
#pragma unroll
        for (int r = 0; r < 4; ++r) {
            const int row = g * 4 + r;
            float4 v0 = xr[(size_t)row * 128 + lane];
            float4 v1 = xr[(size_t)row * 128 + 64 + lane];
            unsigned long long m0 = __ballot(v0.x >= 0.0f);
            unsigned long long m1 = __ballot(v0.y >= 0.0f);
            unsigned long long m2 = __ballot(v0.z >= 0.0f);
            unsigned long long m3 = __ballot(v0.w >= 0.0f);
            unsigned long long m4 = __ballot(v1.x >= 0.0f);
            unsigned long long m5 = __ballot(v1.y >= 0.0f);
            unsigned long long m6 = __ballot(v1.z >= 0.0f);
            unsigned long long m7 = __ballot(v1.w >= 0.0f);
            if (lane == 0) {
                uint4* p = (uint4*)(xb + (size_t)row * KW);
                uint4 q0 = {(uint32_t)m0, (uint32_t)(m0 >> 32),
                            (uint32_t)m1, (uint32_t)(m1 >> 32)};
                uint4 q1 = {(uint32_t)m2, (uint32_t)(m2 >> 32),
                            (uint32_t)m3, (uint32_t)(m3 >> 32)};
                uint4 q2 = {(uint32_t)m4, (uint32_t)(m4 >> 32),
                            (uint32_t)m5, (uint32_t)(m5 >> 32)};
                uint4 q3 = {(uint32_t)m6, (uint32_t)(m6 >> 32),
                            (uint32_t)m7, (uint32_t)(m7 >> 32)};
                p[0] = q0; p[1] = q1; p[2] = q2; p[3] = q3;
            }
        }
    } else {
        // ---- w pack (transposed bit-planes): 128 blocks x 4 waves ----
        const int o = ((blockIdx.x - 2048) * 256 + (int)threadIdx.x) >> 6; // 0..511
        const float t = thr[o];
        const float4* wr = (const float4*)(w + (size_t)o * IN_F);
#pragma unroll
        for (int j = 0; j < 2; ++j) {
            float4 v = wr[j * 64 + lane];
            float vals[4] = {v.x - t, v.y - t, v.z - t, v.w - t};
#pragma unroll
            for (int c = 0; c < 4; ++c) {
                unsigned long long m = __ballot(vals[c] >= 0.0f);
                if (lane == 0) {
                    wbT[(j * 8 + c * 2 + 0) * OUT_F + o] = (uint32_t)m;
                    wbT[(j * 8 + c * 2 + 1) * OUT_F + o] = (uint32_t)(m >> 32);
                }
            }
        }
    }
}

// ---------------------------------------------------------------------------
// Kernel 2: binary GEMM from packed bits. Pure write stream: reads only
// 2 MB xb (L2-resident) + 32 KB wbT. Wave gw owns og = gw&1 (256 cols,
// lane -> 4 cols, wv = 64 VGPRs) and rows row_base + j*2048. Depth-2
// prefetch of xb row words; non-temporal float4 stores.
// ---------------------------------------------------------------------------
__global__ __launch_bounds__(256, 4) void bgemm_kernel(
    const uint32_t* __restrict__ xb,    // [TOKENS][KW]
    const uint32_t* __restrict__ wbT,   // [KW][OUT_F]
    const float*    __restrict__ shift, // [1]
    float*          __restrict__ out)   // [TOKENS][OUT_F]
{
    const int lane = threadIdx.x & 63;
    const int wid  = threadIdx.x >> 6;
    const int gw   = blockIdx.x * 4 + wid;      // 0..4095
    const int og   = gw & 1;
    const int row_base = gw >> 1;               // 0..2047

    // --- weight bits for this wave's 256 columns: 64 VGPRs, loaded once ---
    uint32_t wv[KW][4];
    const uint32_t* wp = wbT + og * 256 + lane * 4;
#pragma unroll
    for (int k = 0; k < KW; ++k) {
        uint4 v = *(const uint4*)(wp + k * OUT_F);
        wv[k][0] = v.x; wv[k][1] = v.y; wv[k][2] = v.z; wv[k][3] = v.w;
    }

    // scale = 2^round(clip(shift, -8, 0)), round-half-even == rintf
    float s = shift[0];
    s = fminf(fmaxf(s, -8.0f), 0.0f);
    const float scale   = exp2f(rintf(s));
    const float negtwos = -2.0f * scale;
    const float basev   = (float)IN_F * scale;

    const uint4* xbr = (const uint4*)xb;        // row r = xbr[r*4 .. r*4+3]

    // depth-2 row-slot prefetch (wave-uniform addresses)
    uint4 a[2][4];
#pragma unroll
    for (int q = 0; q < 4; ++q) a[0][q] = xbr[(size_t)row_base * 4 + q];
#pragma unroll
    for (int q = 0; q < 4; ++q) a[1][q] = xbr[(size_t)(row_base + 2048) * 4 + q];

#pragma unroll
    for (int j = 0; j < 16; ++j) {
        const int slot = j & 1;
        const int row  = row_base + j * 2048;

        uint32_t xw[KW] = {
            a[slot][0].x, a[slot][0].y, a[slot][0].z, a[slot][0].w,
            a[slot][1].x, a[slot][1].y, a[slot][1].z, a[slot][1].w,
            a[slot][2].x, a[slot][2].y, a[slot][2].z, a[slot][2].w,
            a[slot][3].x, a[slot][3].y, a[slot][3].z, a[slot][3].w};

        // prefetch row j+2 into the freed slot
        if (j < 14) {
            const size_t nb = (size_t)(row + 4096) * 4;
#pragma unroll
            for (int q = 0; q < 4; ++q) a[slot][q] = xbr[nb + q];
        }

        uint32_t acc0 = 0, acc1 = 0, acc2 = 0, acc3 = 0;
#pragma unroll
        for (int k = 0; k < KW; ++k) {
            acc0 += __popc(xw[k] ^ wv[k][0]);
            acc1 += __popc(xw[k] ^ wv[k][1]);
            acc2 += __popc(xw[k] ^ wv[k][2]);
            acc3 += __popc(xw[k] ^ wv[k][3]);
        }

        f32x4 o4;
        o4.x = fmaf(negtwos, (float)acc0, basev);
        o4.y = fmaf(negtwos, (float)acc1, basev);
        o4.z = fmaf(negtwos, (float)acc2, basev);
        o4.w = fmaf(negtwos, (float)acc3, basev);
        __builtin_nontemporal_store(o4,
            (f32x4*)&out[(size_t)row * OUT_F + og * 256 + lane * 4]);
    }
}

extern "C" void kernel_launch(void* const* d_in, const int* in_sizes, int n_in,
                              void* d_out, int out_size, void* d_ws, size_t ws_size,
                              hipStream_t stream) {
    const float* x     = (const float*)d_in[0];
    const float* w     = (const float*)d_in[1];
    const float* thr   = (const float*)d_in[2];
    const float* shift = (const float*)d_in[3];
    float*       out   = (float*)d_out;

    uint32_t* wbT = (uint32_t*)d_ws;                         // 32 KB
    uint32_t* xb  = (uint32_t*)((char*)d_ws + 32768);        // 2 MB

    pack_kernel<<<2048 + 128, 256, 0, stream>>>(x, w, thr, xb, wbT);
    bgemm_kernel<<<1024, 256, 0, stream>>>(xb, wbT, shift, out);
}

// Round 7
// 37.433 us; speedup vs baseline: 2.0652x; 2.0652x over previous
//
#include <hip/hip_runtime.h>
#include <stdint.h>

#define TOKENS 32768
#define IN_F   512
#define OUT_F  512
#define KW     16          // 512 bits -> 16 u32 words per row

typedef float f32x4 __attribute__((ext_vector_type(4)));

// ---------------------------------------------------------------------------
// Bit-packing permutation (identical in both kernels, so XOR+popc dot
// products are unaffected): from a row read as float4[128] (index f, lane l),
// word k = f_hi*8 + c*2 + h holds in bit l the sign of float4 #(f_hi*64+l)
// element c (h selects lanes 0..31 / 32..63).
// ---------------------------------------------------------------------------

// Kernel A: binarize weight (minus per-row threshold) into transposed
// bit-plane layout wbT[k][o]. One wave per output row o.
__global__ __launch_bounds__(256) void binw_kernel(
    const float* __restrict__ w,      // [OUT_F][IN_F]
    const float* __restrict__ thr,    // [OUT_F]
    uint32_t* __restrict__ wbT)       // [KW][OUT_F]
{
    const int o    = (blockIdx.x * 256 + threadIdx.x) >> 6;  // 512 waves total
    const int lane = threadIdx.x & 63;

    const float t = thr[o];
    const float4* wr = (const float4*)(w + (size_t)o * IN_F);
#pragma unroll
    for (int j = 0; j < 2; ++j) {
        float4 v = wr[j * 64 + lane];
        float vals[4] = {v.x - t, v.y - t, v.z - t, v.w - t};
#pragma unroll
        for (int c = 0; c < 4; ++c) {
            unsigned long long m = __ballot(vals[c] >= 0.0f);
            if (lane == 0) {
                wbT[(j * 8 + c * 2 + 0) * OUT_F + o] = (uint32_t)m;
                wbT[(j * 8 + c * 2 + 1) * OUT_F + o] = (uint32_t)(m >> 32);
            }
        }
    }
}

// ---------------------------------------------------------------------------
// Kernel B: fused binarize-x + binary GEMM, weight bits resident in VGPRs
// (round-4 structure). Wave gw owns og = gw&1 (256 cols, lane -> 4 cols)
// and rows row_base + (J0+j)*2048, j=0..7. Depth-3 prefetch (~1.5 KB/wave
// in flight). Template NT: non-temporal vs plain store — within-run A/B,
// one dispatch each on disjoint halves of the row set.
// ---------------------------------------------------------------------------
template <bool NT, int J0>
__global__ __launch_bounds__(256, 4) void bgemm_kernel(
    const float*    __restrict__ x,     // [TOKENS][IN_F]
    const uint32_t* __restrict__ wbT,   // [KW][OUT_F]
    const float*    __restrict__ shift, // [1]
    float*          __restrict__ out)   // [TOKENS][OUT_F]
{
    const int lane = threadIdx.x & 63;
    const int wid  = threadIdx.x >> 6;
    const int gw   = blockIdx.x * 4 + wid;      // 0..4095
    const int og   = gw & 1;
    const int row_base = (gw >> 1) + J0 * 2048; // 8 rows: +j*2048, j=0..7

    // --- weight bits for this wave's 256 columns: 64 VGPRs, loaded once ---
    uint32_t wv[KW][4];
    const uint32_t* wp = wbT + og * 256 + lane * 4;
#pragma unroll
    for (int k = 0; k < KW; ++k) {
        uint4 v = *(const uint4*)(wp + k * OUT_F);
        wv[k][0] = v.x; wv[k][1] = v.y; wv[k][2] = v.z; wv[k][3] = v.w;
    }

    // scale = 2^round(clip(shift, -8, 0)), round-half-even == rintf
    float s = shift[0];
    s = fminf(fmaxf(s, -8.0f), 0.0f);
    const float scale   = exp2f(rintf(s));
    const float negtwos = -2.0f * scale;
    const float basev   = (float)IN_F * scale;

    const float4* xr = (const float4*)x;

    // three row slots in flight (depth-3 prefetch)
    float4 a[3][2];
#pragma unroll
    for (int p = 0; p < 3; ++p) {
        const size_t rb = (size_t)(row_base + p * 2048) * 128;
        a[p][0] = xr[rb + lane];
        a[p][1] = xr[rb + 64 + lane];
    }

#pragma unroll
    for (int j = 0; j < 8; ++j) {
        const int slot = j % 3;                  // static after full unroll
        const int row  = row_base + j * 2048;

        // 1) ballot-pack row j -> wave-uniform (SGPR) words, freeing slot
        uint32_t xw[KW];
        {
            unsigned long long m;
            m = __ballot(a[slot][0].x >= 0.0f); xw[0]  = (uint32_t)m; xw[1]  = (uint32_t)(m >> 32);
            m = __ballot(a[slot][0].y >= 0.0f); xw[2]  = (uint32_t)m; xw[3]  = (uint32_t)(m >> 32);
            m = __ballot(a[slot][0].z >= 0.0f); xw[4]  = (uint32_t)m; xw[5]  = (uint32_t)(m >> 32);
            m = __ballot(a[slot][0].w >= 0.0f); xw[6]  = (uint32_t)m; xw[7]  = (uint32_t)(m >> 32);
            m = __ballot(a[slot][1].x >= 0.0f); xw[8]  = (uint32_t)m; xw[9]  = (uint32_t)(m >> 32);
            m = __ballot(a[slot][1].y >= 0.0f); xw[10] = (uint32_t)m; xw[11] = (uint32_t)(m >> 32);
            m = __ballot(a[slot][1].z >= 0.0f); xw[12] = (uint32_t)m; xw[13] = (uint32_t)(m >> 32);
            m = __ballot(a[slot][1].w >= 0.0f); xw[14] = (uint32_t)m; xw[15] = (uint32_t)(m >> 32);
        }

        // 2) issue depth-3 prefetch of row j+3 into the freed slot
        if (j < 5) {
            const size_t nb = (size_t)(row + 3 * 2048) * 128;
            a[slot][0] = xr[nb + lane];
            a[slot][1] = xr[nb + 64 + lane];
        }

        // 3) XOR + popcount accumulate (wave-uniform xw vs per-lane wv)
        uint32_t acc0 = 0, acc1 = 0, acc2 = 0, acc3 = 0;
#pragma unroll
        for (int k = 0; k < KW; ++k) {
            acc0 += __popc(xw[k] ^ wv[k][0]);
            acc1 += __popc(xw[k] ^ wv[k][1]);
            acc2 += __popc(xw[k] ^ wv[k][2]);
            acc3 += __popc(xw[k] ^ wv[k][3]);
        }

        // 4) (512 - 2*acc) * scale, exact in fp32
        f32x4 o4;
        o4.x = fmaf(negtwos, (float)acc0, basev);
        o4.y = fmaf(negtwos, (float)acc1, basev);
        o4.z = fmaf(negtwos, (float)acc2, basev);
        o4.w = fmaf(negtwos, (float)acc3, basev);
        f32x4* dst = (f32x4*)&out[(size_t)row * OUT_F + og * 256 + lane * 4];
        if (NT) __builtin_nontemporal_store(o4, dst);
        else    *dst = o4;
    }
}

extern "C" void kernel_launch(void* const* d_in, const int* in_sizes, int n_in,
                              void* d_out, int out_size, void* d_ws, size_t ws_size,
                              hipStream_t stream) {
    const float* x     = (const float*)d_in[0];
    const float* w     = (const float*)d_in[1];
    const float* thr   = (const float*)d_in[2];
    const float* shift = (const float*)d_in[3];
    float*       out   = (float*)d_out;
    uint32_t*    wbT   = (uint32_t*)d_ws;   // 16*512*4 = 32 KB scratch

    binw_kernel<<<128, 256, 0, stream>>>(w, thr, wbT);
    // Within-run A/B: NT stores on rows [0, 16384), plain on [16384, 32768).
    bgemm_kernel<true, 0><<<1024, 256, 0, stream>>>(x, wbT, shift, out);
    bgemm_kernel<false, 8><<<1024, 256, 0, stream>>>(x, wbT, shift, out);
}